// Round 14
// baseline (161.549 us; speedup 1.0000x reference)
//
#include <hip/hip_runtime.h>
#include <hip/hip_bf16.h>
#include <cmath>

#define DIM 128
#define HEADS 8
#define NBATCH 2
#define NQ 6400   /* 80*80 */
#define NKV 1600  /* 40*40 */
#define NC 50     /* kv chunks of 32 */
#define BN_EPS 1e-5f
#define LOG2E 1.4426950408889634f

typedef __bf16 bf16_t;
typedef __attribute__((ext_vector_type(8))) __bf16 bf16x8;
typedef __attribute__((ext_vector_type(16))) float f32x16;

union BF8U { bf16x8 v; unsigned u[4]; };

// pack two f32 -> packed bf16 (a->lo, b->hi); lowers to v_cvt_pk_bf16_f32 (RNE)
__device__ inline unsigned packbf2(float a, float b) {
  union { __hip_bfloat162 v; unsigned u; } r;
  r.v = __float22bfloat162_rn(make_float2(a, b));
  return r.u;
}

__device__ inline unsigned short f2bf(float v) {
  unsigned u = __float_as_uint(v);
  return (unsigned short)((u + 0x7FFFu + ((u >> 16) & 1u)) >> 16);
}

// ---------------------------------------------------------------------------
// prep_all: fused transpose + coalesced im2col + weight cast + Vp denom fill.
// blocks [0,1600):    x (B,128,6400) f32 -> Xb (B,6400,128) bf16 (LDS tile)
// blocks [1600,2240): im2col, LDS-tiled & two-side coalesced.
// blocks [2240,2880): e-indexed aux: weight cast + Vp lane-16 fill.
// ---------------------------------------------------------------------------
__global__ __launch_bounds__(256) void prep_all(
    const float* __restrict__ x,
    const float* __restrict__ qw, const float* __restrict__ kw,
    const float* __restrict__ vw, const float* __restrict__ pw,
    const float* __restrict__ srw,
    unsigned short* __restrict__ Xb,
    unsigned short* __restrict__ Wb,
    unsigned short* __restrict__ X4b,
    unsigned short* __restrict__ Vp)
{
  int t = threadIdx.x;
  int bx = blockIdx.x;
  if (bx < 1600) {                 // ---- transpose part ----
    __shared__ float tile[32][33];
    int tx = t & 31, ty = t >> 5;
    int b = bx / 800;
    int rem = bx % 800;
    int c0 = (rem / 200) * 32, s0 = (rem % 200) * 32;
#pragma unroll
    for (int r = 0; r < 32; r += 8)
      tile[ty + r][tx] = x[((size_t)b * DIM + c0 + ty + r) * NQ + s0 + tx];
    __syncthreads();
#pragma unroll
    for (int r = 0; r < 32; r += 8)
      Xb[((size_t)b * NQ + s0 + ty + r) * DIM + c0 + tx] = f2bf(tile[tx][ty + r]);
    return;
  }
  if (bx < 2240) {                 // ---- im2col part (640 blocks) ----
    __shared__ float itile[16][164];   // 164 pad: 2-way LDS alias only (free)
    int idx0 = bx - 1600;              // b(2) x i(40) x cg(8)
    int b  = idx0 / 320;
    int rem = idx0 % 320;
    int i  = rem / 8;
    int c0 = (rem % 8) * 16;
    const float* xb = x + ((size_t)b * DIM + c0) * NQ + (size_t)i * 160;
#pragma unroll
    for (int k = 0; k < 10; ++k) {
      int idx = t + k * 256;           // 2560 total
      int r = idx / 160, col = idx % 160;
      itile[r][col] = xb[(size_t)r * NQ + col];
    }
    __syncthreads();
    unsigned short* ob = X4b + ((size_t)b * NKV + (size_t)i * 40) * 512 + c0 * 4;
#pragma unroll
    for (int k = 0; k < 10; ++k) {
      int idx = t + k * 256;           // 2560 total
      int j = idx >> 6, cc = idx & 63;
      int cr = cc >> 2, ky = (cc >> 1) & 1, kx = cc & 1;
      ob[(size_t)j * 512 + cc] = f2bf(itile[cr][ky * 80 + 2 * j + kx]);
    }
    return;
  }
  // ---- aux part ----
  int e = (bx - 2240) * 256 + t;     // 163,840 range
  if (e < 131072) {                  // weight cast: q|k|v|proj 16384 ea | sr 65536
    const float* src; int idx;
    if (e < 16384)      { src = qw;  idx = e; }
    else if (e < 32768) { src = kw;  idx = e - 16384; }
    else if (e < 49152) { src = vw;  idx = e - 32768; }
    else if (e < 65536) { src = pw;  idx = e - 49152; }
    else                { src = srw; idx = e - 65536; }
    Wb[e] = f2bf(src[idx]);
  }
  if (e < NBATCH * HEADS * NC * 32) {   // Vp lane-16 (denominator) fill: 25600
    int cid = e >> 5;
    int pos = e & 31;
    size_t addr = (size_t)cid * 1024 + 256 + ((pos & 16) ? 512 : 0) + (pos & 15);
    Vp[addr] = 0x3F80;               // 1.0 bf16
  }
}

// ---------------------------------------------------------------------------
// Fused q + (sr -> k -> v) GEMM (round-11/12/13 verbatim). Block 256 = 4 waves.
// blocks [0,50):    sr tile (C=512) -> BN+ReLU -> LDS -> k GEMM + v GEMM with
//                   fragment-major Kp/Vp epilogues.
// blocks [50,250):  q tile of Xb (C=128) -> Qb bf16 token-major, *SCALE*log2e
// ---------------------------------------------------------------------------
__global__ __launch_bounds__(256) void mgemm_qsrkv(
    const bf16_t* __restrict__ Xb, const bf16_t* __restrict__ X4b,
    const bf16_t* __restrict__ Wb,
    const float* __restrict__ q_b, const float* __restrict__ sr_b,
    const float* __restrict__ k_b, const float* __restrict__ v_b,
    const float* __restrict__ bng, const float* __restrict__ bnb,
    const float* __restrict__ bnm, const float* __restrict__ bnv,
    unsigned short* __restrict__ Qb,
    unsigned short* __restrict__ Kp, unsigned short* __restrict__ Vp,
    float sl)
{
  __shared__ __align__(16) unsigned short xs[32][136];
  int t = threadIdx.x;
  int ln = t & 31, hf = (t >> 5) & 1, wid = t >> 6;
  int b = blockIdx.y;
  int o = wid * 32 + ln;

  if (blockIdx.x < 50) {             // ---- sr -> k -> v part ----
    int s0 = blockIdx.x * 32;
    const bf16_t* arow = &X4b[((size_t)b * NKV + s0 + ln) * 512 + hf * 8];
    const bf16_t* brow = &Wb[65536 + (size_t)o * 512 + hf * 8];
    f32x16 acc = {};
#pragma unroll 8
    for (int c0 = 0; c0 < 512; c0 += 16) {
      bf16x8 af = *(const bf16x8*)&arow[c0];
      bf16x8 bf = *(const bf16x8*)&brow[c0];
      acc = __builtin_amdgcn_mfma_f32_32x32x16_bf16(af, bf, acc, 0, 0, 0);
    }
    float bv = sr_b[o];
    float inv = bng[o] / sqrtf(bnv[o] + BN_EPS);
    float b2 = bnb[o] - bnm[o] * inv;
#pragma unroll
    for (int g = 0; g < 4; ++g)
#pragma unroll
      for (int j = 0; j < 4; ++j) {
        int s = 8 * g + 4 * hf + j;
        xs[s][o] = f2bf(fmaxf((acc[4 * g + j] + bv) * inv + b2, 0.f));
      }
    __syncthreads();

    // k + v GEMMs (C=128) off the LDS tile
    const unsigned short* ar2 = &xs[ln][hf * 8];
    const bf16_t* kbrow = &Wb[16384 + (size_t)o * DIM + hf * 8];
    const bf16_t* vbrow = &Wb[32768 + (size_t)o * DIM + hf * 8];
    f32x16 ka = {}, va = {};
#pragma unroll
    for (int c0 = 0; c0 < 128; c0 += 16) {
      bf16x8 af = *(const bf16x8*)&ar2[c0];
      bf16x8 kb = *(const bf16x8*)&kbrow[c0];
      bf16x8 vb = *(const bf16x8*)&vbrow[c0];
      ka = __builtin_amdgcn_mfma_f32_32x32x16_bf16(af, kb, ka, 0, 0, 0);
      va = __builtin_amdgcn_mfma_f32_32x32x16_bf16(af, vb, va, 0, 0, 0);
    }
    int hloc = o >> 4, d = o & 15;
    {
      float kb2 = k_b[o];
      size_t CB = (((size_t)b * HEADS + hloc) * NC + (s0 >> 5)) * 512;
#pragma unroll
      for (int g = 0; g < 4; ++g)
#pragma unroll
        for (int j = 0; j < 4; ++j) {
          int sl2 = 8 * g + 4 * hf + j;              // s_local row
          Kp[CB + sl2 * 16 + d] = f2bf(ka[4 * g + j] + kb2);
        }
    }
    {
      float vb2 = v_b[o];
      size_t CB = (((size_t)b * HEADS + hloc) * NC + (s0 >> 5)) * 1024;
      uint4 w0, w1;
      w0.x = packbf2(va[0] + vb2, va[1] + vb2);
      w0.y = packbf2(va[2] + vb2, va[3] + vb2);
      w0.z = packbf2(va[4] + vb2, va[5] + vb2);
      w0.w = packbf2(va[6] + vb2, va[7] + vb2);
      w1.x = packbf2(va[8] + vb2, va[9] + vb2);
      w1.y = packbf2(va[10] + vb2, va[11] + vb2);
      w1.z = packbf2(va[12] + vb2, va[13] + vb2);
      w1.w = packbf2(va[14] + vb2, va[15] + vb2);
      *(uint4*)&Vp[CB + d * 16 + hf * 8] = w0;       // va block
      *(uint4*)&Vp[CB + 512 + d * 16 + hf * 8] = w1; // vb block
    }
  } else {                           // ---- q part (C = 128) ----
    int s0 = (blockIdx.x - 50) * 32;
    const bf16_t* arow = &Xb[((size_t)b * NQ + s0 + ln) * DIM + hf * 8];
    const bf16_t* brow = &Wb[(size_t)o * DIM + hf * 8];
    f32x16 acc = {};
#pragma unroll
    for (int c0 = 0; c0 < 128; c0 += 16) {
      bf16x8 af = *(const bf16x8*)&arow[c0];
      bf16x8 bf = *(const bf16x8*)&brow[c0];
      acc = __builtin_amdgcn_mfma_f32_32x32x16_bf16(af, bf, acc, 0, 0, 0);
    }
    float bv = q_b[o];
#pragma unroll
    for (int g = 0; g < 4; ++g)
#pragma unroll
      for (int j = 0; j < 4; ++j) {
        int s = s0 + 8 * g + 4 * hf + j;
        Qb[((size_t)b * NQ + s) * DIM + o] = f2bf((acc[4 * g + j] + bv) * sl);
      }
  }
}

// ---------------------------------------------------------------------------
// MFMA attention, software-pipelined (round-12 body), now with the residency
// cap LIFTED: __launch_bounds__(256,8). VGPR=40 measured -> 8 waves/EU fits;
// all 6.25 blocks/CU co-resident (was capped at 4 -> 33% occupancy).
// kv-split=2, fragment-major K/V, 2-deep prefetch, S one chunk ahead, dual
// accumulators. grid (50, 8, 4): z = b + 2*half. block 256.
// ---------------------------------------------------------------------------
__global__ __launch_bounds__(256, 8) void attn_split(
    const bf16_t* __restrict__ Qb, const bf16_t* __restrict__ Kp,
    const bf16_t* __restrict__ Vp, unsigned short* __restrict__ Pb,
    float* __restrict__ Lsum)
{
  const int t = threadIdx.x;
  const int ln = t & 31, hf = (t >> 5) & 1, wid = t >> 6;
  const int h = blockIdx.y;
  const int b = blockIdx.z & 1, half = blockIdx.z >> 1;
  const int q0 = blockIdx.x * 128 + wid * 32;

  bf16x8 qf = *(const bf16x8*)&Qb[((size_t)b * NQ + q0 + ln) * DIM + h * 16 + hf * 8];
  const int bh = b * HEADS + h;
  const bf16_t* kc = &Kp[((size_t)bh * NC + half * 25) * 512 + ln * 16 + hf * 8];
  const bf16_t* vc = &Vp[((size_t)bh * NC + half * 25) * 1024 + ln * 16 + hf * 8];

  f32x16 acc0 = {}, acc1 = {};
  const f32x16 zero = {};

  bf16x8 kf0 = *(const bf16x8*)kc;
  bf16x8 va0 = *(const bf16x8*)vc;
  bf16x8 vb0 = *(const bf16x8*)(vc + 512);
  bf16x8 kf1 = *(const bf16x8*)(kc + 512);
  bf16x8 va1 = *(const bf16x8*)(vc + 1024);
  bf16x8 vb1 = *(const bf16x8*)(vc + 1536);

  f32x16 S0 = __builtin_amdgcn_mfma_f32_32x32x16_bf16(kf0, qf, zero, 0, 0, 0);

  for (int c = 0; c < 25; ++c) {
    int cn = (c + 2 < 25) ? c + 2 : 24;    // 2-deep prefetch (clamped)
    bf16x8 kf2 = *(const bf16x8*)(kc + (size_t)cn * 512);
    bf16x8 va2 = *(const bf16x8*)(vc + (size_t)cn * 1024);
    bf16x8 vb2 = *(const bf16x8*)(vc + (size_t)cn * 1024 + 512);

    f32x16 S1 = __builtin_amdgcn_mfma_f32_32x32x16_bf16(kf1, qf, zero, 0, 0, 0);

    BF8U f0, f1;
#pragma unroll
    for (int i = 0; i < 4; ++i) {
      f0.u[i] = packbf2(__builtin_amdgcn_exp2f(S0[2 * i]),
                        __builtin_amdgcn_exp2f(S0[2 * i + 1]));
      f1.u[i] = packbf2(__builtin_amdgcn_exp2f(S0[8 + 2 * i]),
                        __builtin_amdgcn_exp2f(S0[9 + 2 * i]));
    }

    acc0 = __builtin_amdgcn_mfma_f32_32x32x16_bf16(va0, f0.v, acc0, 0, 0, 0);
    acc1 = __builtin_amdgcn_mfma_f32_32x32x16_bf16(vb0, f1.v, acc1, 0, 0, 0);

    S0 = S1;
    kf0 = kf1; va0 = va1; vb0 = vb1;
    kf1 = kf2; va1 = va2; vb1 = vb2;
  }

  f32x16 acc;
#pragma unroll
  for (int i = 0; i < 16; ++i) acc[i] = acc0[i] + acc1[i];

  // acc: col q = ln, row d = (r&3)+8*(r>>2)+4*hf. Row16 (denom) = acc[8]@hf0.
  unsigned short* prow =
      &Pb[(size_t)(half * 2 + b) * (NQ * DIM) + (size_t)(q0 + ln) * DIM + h * 16 + 4 * hf];
  uint2 w0, w1;
  w0.x = packbf2(acc[0], acc[1]); w0.y = packbf2(acc[2], acc[3]);
  w1.x = packbf2(acc[4], acc[5]); w1.y = packbf2(acc[6], acc[7]);
  *(uint2*)&prow[0] = w0;
  *(uint2*)&prow[8] = w1;
  if (!hf)
    Lsum[(size_t)(half * 2 + b) * (HEADS * NQ) + (size_t)h * NQ + q0 + ln] = acc[8];
}

// ---------------------------------------------------------------------------
// proj_comb: fused combine (2 halves) + reference scramble + proj GEMM.
// grid (200, 2), block 256.
// ---------------------------------------------------------------------------
__global__ __launch_bounds__(256) void proj_comb(
    const unsigned short* __restrict__ Pb, const float* __restrict__ Lsum,
    const bf16_t* __restrict__ Wb, const float* __restrict__ p_b,
    float* __restrict__ Out)
{
  __shared__ __align__(16) unsigned short As[32][136];
  int t = threadIdx.x;
  int b = blockIdx.y;
  int s0 = blockIdx.x * 32;

  {
    int tx = t & 31, cg = t >> 5;          // lane sweeps s (coalesced in f)
#pragma unroll
    for (int it = 0; it < 16; ++it) {
      int c = cg * 16 + it;
      int f = c * NQ + s0 + tx;            // flat att index = n*128 + h*16+d
      int n = f >> 7, hh = (f >> 4) & 7;
      float p0 = __uint_as_float((unsigned)Pb[(size_t)b * (NQ * DIM) + f] << 16);
      float p1 = __uint_as_float((unsigned)Pb[(size_t)(2 + b) * (NQ * DIM) + f] << 16);
      float L = Lsum[(size_t)b * (HEADS * NQ) + (size_t)hh * NQ + n] +
                Lsum[(size_t)(2 + b) * (HEADS * NQ) + (size_t)hh * NQ + n];
      As[tx][c] = f2bf((p0 + p1) / L);
    }
  }
  __syncthreads();

  int ln = t & 31, hf = (t >> 5) & 1, wid = t >> 6;
  int o = wid * 32 + ln;
  const bf16_t* brow = &Wb[49152 + (size_t)o * DIM + hf * 8];
  const unsigned short* arow = &As[ln][hf * 8];
  f32x16 acc = {};
#pragma unroll
  for (int c0 = 0; c0 < 128; c0 += 16) {
    bf16x8 af = *(const bf16x8*)&arow[c0];
    bf16x8 bf = *(const bf16x8*)&brow[c0];
    acc = __builtin_amdgcn_mfma_f32_32x32x16_bf16(af, bf, acc, 0, 0, 0);
  }
  float bv = p_b[o];
  float* obase = &Out[((size_t)b * DIM + o) * NQ + s0 + 4 * hf];
#pragma unroll
  for (int g = 0; g < 4; ++g) {
    float4 r;
    r.x = acc[4 * g + 0] + bv; r.y = acc[4 * g + 1] + bv;
    r.z = acc[4 * g + 2] + bv; r.w = acc[4 * g + 3] + bv;
    *(float4*)&obase[8 * g] = r;
  }
}

// ---------------------------------------------------------------------------
extern "C" void kernel_launch(void* const* d_in, const int* in_sizes, int n_in,
                              void* d_out, int out_size, void* d_ws, size_t ws_size,
                              hipStream_t stream)
{
  const float* x    = (const float*)d_in[0];
  const float* q_w  = (const float*)d_in[1];
  const float* q_b  = (const float*)d_in[2];
  const float* k_w  = (const float*)d_in[3];
  const float* k_b  = (const float*)d_in[4];
  const float* v_w  = (const float*)d_in[5];
  const float* v_b  = (const float*)d_in[6];
  const float* sr_w = (const float*)d_in[7];
  const float* sr_b = (const float*)d_in[8];
  const float* bng  = (const float*)d_in[9];
  const float* bnb  = (const float*)d_in[10];
  const float* bnm  = (const float*)d_in[11];
  const float* bnv  = (const float*)d_in[12];
  const float* p_w  = (const float*)d_in[13];
  const float* p_b  = (const float*)d_in[14];
  float* out = (float*)d_out;

  float* ws = (float*)d_ws;
  // f32-slot layout, no aliasing (~19.9 MB of the 256+ MB ws):
  bf16_t* Xb   = (bf16_t*)(ws);             // [0, 819200)
  bf16_t* X4b  = (bf16_t*)(ws + 819200);    // [819200, 1638400)
  bf16_t* Qb   = (bf16_t*)(ws + 1638400);   // [1638400, 2457600)
  bf16_t* Kp   = (bf16_t*)(ws + 2457600);   // [2457600, 2662400)
  bf16_t* Vp   = (bf16_t*)(ws + 2662400);   // [2662400, 3072000)
  float*  Lsum = ws + 3072000;              // [3072000, 3276800)
  bf16_t* Wb   = (bf16_t*)(ws + 3276800);   // [3276800, 3342336)
  bf16_t* Pb   = (bf16_t*)(ws + 3342336);   // [3342336, 4980736) 4 slices

  const float sl = 0.25f * LOG2E;  // SCALE * log2(e) folded into Q

  // 1. transpose + coalesced im2col + weight cast + Vp denom fill (fused)
  prep_all<<<dim3(2880), dim3(256), 0, stream>>>(
      x, q_w, k_w, v_w, p_w, sr_w,
      (unsigned short*)Xb, (unsigned short*)Wb,
      (unsigned short*)X4b, (unsigned short*)Vp);

  // 2. sr->k->v (blocks 0-49, LDS-fused) + q (blocks 50-249)
  mgemm_qsrkv<<<dim3(250, NBATCH), dim3(256), 0, stream>>>(
      Xb, X4b, Wb, q_b, sr_b, k_b, v_b, bng, bnb, bnm, bnv,
      (unsigned short*)Qb, (unsigned short*)Kp, (unsigned short*)Vp, sl);

  // 3. attention partials (kv-split = 2, pipelined, 8 waves/EU residency)
  attn_split<<<dim3(NQ / 128, HEADS, 4), dim3(256), 0, stream>>>(
      Qb, Kp, Vp, (unsigned short*)Pb, Lsum);

  // 4. combine + scramble + proj -> f32 chan-major final output (B,128,80,80)
  proj_comb<<<dim3(200, NBATCH), dim3(256), 0, stream>>>(
      (const unsigned short*)Pb, Lsum, Wb, p_b, out);
}

// Round 15
// 151.585 us; speedup vs baseline: 1.0657x; 1.0657x over previous
//
#include <hip/hip_runtime.h>
#include <hip/hip_bf16.h>
#include <cmath>

#define DIM 128
#define HEADS 8
#define NBATCH 2
#define NQ 6400   /* 80*80 */
#define NKV 1600  /* 40*40 */
#define NC 50     /* kv chunks of 32 */
#define BN_EPS 1e-5f
#define LOG2E 1.4426950408889634f

typedef __bf16 bf16_t;
typedef __attribute__((ext_vector_type(8))) __bf16 bf16x8;
typedef __attribute__((ext_vector_type(16))) float f32x16;

union BF8U { bf16x8 v; unsigned u[4]; };

// pack two f32 -> packed bf16 (a->lo, b->hi); lowers to v_cvt_pk_bf16_f32 (RNE)
__device__ inline unsigned packbf2(float a, float b) {
  union { __hip_bfloat162 v; unsigned u; } r;
  r.v = __float22bfloat162_rn(make_float2(a, b));
  return r.u;
}

__device__ inline unsigned short f2bf(float v) {
  unsigned u = __float_as_uint(v);
  return (unsigned short)((u + 0x7FFFu + ((u >> 16) & 1u)) >> 16);
}

// ---------------------------------------------------------------------------
// prep_all: fused transpose + coalesced im2col + weight cast + Vp denom fill.
// blocks [0,1600):    x (B,128,6400) f32 -> Xb (B,6400,128) bf16 (LDS tile)
// blocks [1600,2240): im2col, LDS-tiled & two-side coalesced.
// blocks [2240,2880): e-indexed aux: weight cast + Vp lane-16 fill.
// ---------------------------------------------------------------------------
__global__ __launch_bounds__(256) void prep_all(
    const float* __restrict__ x,
    const float* __restrict__ qw, const float* __restrict__ kw,
    const float* __restrict__ vw, const float* __restrict__ pw,
    const float* __restrict__ srw,
    unsigned short* __restrict__ Xb,
    unsigned short* __restrict__ Wb,
    unsigned short* __restrict__ X4b,
    unsigned short* __restrict__ Vp)
{
  int t = threadIdx.x;
  int bx = blockIdx.x;
  if (bx < 1600) {                 // ---- transpose part ----
    __shared__ float tile[32][33];
    int tx = t & 31, ty = t >> 5;
    int b = bx / 800;
    int rem = bx % 800;
    int c0 = (rem / 200) * 32, s0 = (rem % 200) * 32;
#pragma unroll
    for (int r = 0; r < 32; r += 8)
      tile[ty + r][tx] = x[((size_t)b * DIM + c0 + ty + r) * NQ + s0 + tx];
    __syncthreads();
#pragma unroll
    for (int r = 0; r < 32; r += 8)
      Xb[((size_t)b * NQ + s0 + ty + r) * DIM + c0 + tx] = f2bf(tile[tx][ty + r]);
    return;
  }
  if (bx < 2240) {                 // ---- im2col part (640 blocks) ----
    __shared__ float itile[16][164];   // 164 pad: 2-way LDS alias only (free)
    int idx0 = bx - 1600;              // b(2) x i(40) x cg(8)
    int b  = idx0 / 320;
    int rem = idx0 % 320;
    int i  = rem / 8;
    int c0 = (rem % 8) * 16;
    const float* xb = x + ((size_t)b * DIM + c0) * NQ + (size_t)i * 160;
#pragma unroll
    for (int k = 0; k < 10; ++k) {
      int idx = t + k * 256;           // 2560 total
      int r = idx / 160, col = idx % 160;
      itile[r][col] = xb[(size_t)r * NQ + col];
    }
    __syncthreads();
    unsigned short* ob = X4b + ((size_t)b * NKV + (size_t)i * 40) * 512 + c0 * 4;
#pragma unroll
    for (int k = 0; k < 10; ++k) {
      int idx = t + k * 256;           // 2560 total
      int j = idx >> 6, cc = idx & 63;
      int cr = cc >> 2, ky = (cc >> 1) & 1, kx = cc & 1;
      ob[(size_t)j * 512 + cc] = f2bf(itile[cr][ky * 80 + 2 * j + kx]);
    }
    return;
  }
  // ---- aux part ----
  int e = (bx - 2240) * 256 + t;     // 163,840 range
  if (e < 131072) {                  // weight cast: q|k|v|proj 16384 ea | sr 65536
    const float* src; int idx;
    if (e < 16384)      { src = qw;  idx = e; }
    else if (e < 32768) { src = kw;  idx = e - 16384; }
    else if (e < 49152) { src = vw;  idx = e - 32768; }
    else if (e < 65536) { src = pw;  idx = e - 49152; }
    else                { src = srw; idx = e - 65536; }
    Wb[e] = f2bf(src[idx]);
  }
  if (e < NBATCH * HEADS * NC * 32) {   // Vp lane-16 (denominator) fill: 25600
    int cid = e >> 5;
    int pos = e & 31;
    size_t addr = (size_t)cid * 1024 + 256 + ((pos & 16) ? 512 : 0) + (pos & 15);
    Vp[addr] = 0x3F80;               // 1.0 bf16
  }
}

// ---------------------------------------------------------------------------
// Fused q + (sr -> k -> v) GEMM (round-13 verbatim). Block 256 = 4 waves.
// blocks [0,50):    sr tile (C=512) -> BN+ReLU -> LDS -> k GEMM + v GEMM with
//                   fragment-major Kp/Vp epilogues.
// blocks [50,250):  q tile of Xb (C=128) -> Qb bf16 token-major, *SCALE*log2e
// ---------------------------------------------------------------------------
__global__ __launch_bounds__(256) void mgemm_qsrkv(
    const bf16_t* __restrict__ Xb, const bf16_t* __restrict__ X4b,
    const bf16_t* __restrict__ Wb,
    const float* __restrict__ q_b, const float* __restrict__ sr_b,
    const float* __restrict__ k_b, const float* __restrict__ v_b,
    const float* __restrict__ bng, const float* __restrict__ bnb,
    const float* __restrict__ bnm, const float* __restrict__ bnv,
    unsigned short* __restrict__ Qb,
    unsigned short* __restrict__ Kp, unsigned short* __restrict__ Vp,
    float sl)
{
  __shared__ __align__(16) unsigned short xs[32][136];
  int t = threadIdx.x;
  int ln = t & 31, hf = (t >> 5) & 1, wid = t >> 6;
  int b = blockIdx.y;
  int o = wid * 32 + ln;

  if (blockIdx.x < 50) {             // ---- sr -> k -> v part ----
    int s0 = blockIdx.x * 32;
    const bf16_t* arow = &X4b[((size_t)b * NKV + s0 + ln) * 512 + hf * 8];
    const bf16_t* brow = &Wb[65536 + (size_t)o * 512 + hf * 8];
    f32x16 acc = {};
#pragma unroll 8
    for (int c0 = 0; c0 < 512; c0 += 16) {
      bf16x8 af = *(const bf16x8*)&arow[c0];
      bf16x8 bf = *(const bf16x8*)&brow[c0];
      acc = __builtin_amdgcn_mfma_f32_32x32x16_bf16(af, bf, acc, 0, 0, 0);
    }
    float bv = sr_b[o];
    float inv = bng[o] / sqrtf(bnv[o] + BN_EPS);
    float b2 = bnb[o] - bnm[o] * inv;
#pragma unroll
    for (int g = 0; g < 4; ++g)
#pragma unroll
      for (int j = 0; j < 4; ++j) {
        int s = 8 * g + 4 * hf + j;
        xs[s][o] = f2bf(fmaxf((acc[4 * g + j] + bv) * inv + b2, 0.f));
      }
    __syncthreads();

    // k + v GEMMs (C=128) off the LDS tile
    const unsigned short* ar2 = &xs[ln][hf * 8];
    const bf16_t* kbrow = &Wb[16384 + (size_t)o * DIM + hf * 8];
    const bf16_t* vbrow = &Wb[32768 + (size_t)o * DIM + hf * 8];
    f32x16 ka = {}, va = {};
#pragma unroll
    for (int c0 = 0; c0 < 128; c0 += 16) {
      bf16x8 af = *(const bf16x8*)&ar2[c0];
      bf16x8 kb = *(const bf16x8*)&kbrow[c0];
      bf16x8 vb = *(const bf16x8*)&vbrow[c0];
      ka = __builtin_amdgcn_mfma_f32_32x32x16_bf16(af, kb, ka, 0, 0, 0);
      va = __builtin_amdgcn_mfma_f32_32x32x16_bf16(af, vb, va, 0, 0, 0);
    }
    int hloc = o >> 4, d = o & 15;
    {
      float kb2 = k_b[o];
      size_t CB = (((size_t)b * HEADS + hloc) * NC + (s0 >> 5)) * 512;
#pragma unroll
      for (int g = 0; g < 4; ++g)
#pragma unroll
        for (int j = 0; j < 4; ++j) {
          int sl2 = 8 * g + 4 * hf + j;              // s_local row
          Kp[CB + sl2 * 16 + d] = f2bf(ka[4 * g + j] + kb2);
        }
    }
    {
      float vb2 = v_b[o];
      size_t CB = (((size_t)b * HEADS + hloc) * NC + (s0 >> 5)) * 1024;
      uint4 w0, w1;
      w0.x = packbf2(va[0] + vb2, va[1] + vb2);
      w0.y = packbf2(va[2] + vb2, va[3] + vb2);
      w0.z = packbf2(va[4] + vb2, va[5] + vb2);
      w0.w = packbf2(va[6] + vb2, va[7] + vb2);
      w1.x = packbf2(va[8] + vb2, va[9] + vb2);
      w1.y = packbf2(va[10] + vb2, va[11] + vb2);
      w1.z = packbf2(va[12] + vb2, va[13] + vb2);
      w1.w = packbf2(va[14] + vb2, va[15] + vb2);
      *(uint4*)&Vp[CB + d * 16 + hf * 8] = w0;       // va block
      *(uint4*)&Vp[CB + 512 + d * 16 + hf * 8] = w1; // vb block
    }
  } else {                           // ---- q part (C = 128) ----
    int s0 = (blockIdx.x - 50) * 32;
    const bf16_t* arow = &Xb[((size_t)b * NQ + s0 + ln) * DIM + hf * 8];
    const bf16_t* brow = &Wb[(size_t)o * DIM + hf * 8];
    f32x16 acc = {};
#pragma unroll
    for (int c0 = 0; c0 < 128; c0 += 16) {
      bf16x8 af = *(const bf16x8*)&arow[c0];
      bf16x8 bf = *(const bf16x8*)&brow[c0];
      acc = __builtin_amdgcn_mfma_f32_32x32x16_bf16(af, bf, acc, 0, 0, 0);
    }
    float bv = q_b[o];
#pragma unroll
    for (int g = 0; g < 4; ++g)
#pragma unroll
      for (int j = 0; j < 4; ++j) {
        int s = s0 + 8 * g + 4 * hf + j;
        Qb[((size_t)b * NQ + s) * DIM + o] = f2bf((acc[4 * g + j] + bv) * sl);
      }
  }
}

// ---------------------------------------------------------------------------
// MFMA attention, software-pipelined (round-12/13 body). Launch bounds have
// NO min-waves arg: (256,4) capped residency (round 13: occ 33%), (256,8)
// forced VGPR 40->32 and spilled ~13 MB to scratch (round 14: FETCH+WRITE
// ballooned, dur regressed). Natural allocation (~40-56 VGPR) lets HW run
// up to the supply limit (6.25 blocks/CU) without spill.
// kv-split=2, fragment-major K/V, 2-deep prefetch, S one chunk ahead, dual
// accumulators. grid (50, 8, 4): z = b + 2*half. block 256.
// ---------------------------------------------------------------------------
__global__ __launch_bounds__(256) void attn_split(
    const bf16_t* __restrict__ Qb, const bf16_t* __restrict__ Kp,
    const bf16_t* __restrict__ Vp, unsigned short* __restrict__ Pb,
    float* __restrict__ Lsum)
{
  const int t = threadIdx.x;
  const int ln = t & 31, hf = (t >> 5) & 1, wid = t >> 6;
  const int h = blockIdx.y;
  const int b = blockIdx.z & 1, half = blockIdx.z >> 1;
  const int q0 = blockIdx.x * 128 + wid * 32;

  bf16x8 qf = *(const bf16x8*)&Qb[((size_t)b * NQ + q0 + ln) * DIM + h * 16 + hf * 8];
  const int bh = b * HEADS + h;
  const bf16_t* kc = &Kp[((size_t)bh * NC + half * 25) * 512 + ln * 16 + hf * 8];
  const bf16_t* vc = &Vp[((size_t)bh * NC + half * 25) * 1024 + ln * 16 + hf * 8];

  f32x16 acc0 = {}, acc1 = {};
  const f32x16 zero = {};

  bf16x8 kf0 = *(const bf16x8*)kc;
  bf16x8 va0 = *(const bf16x8*)vc;
  bf16x8 vb0 = *(const bf16x8*)(vc + 512);
  bf16x8 kf1 = *(const bf16x8*)(kc + 512);
  bf16x8 va1 = *(const bf16x8*)(vc + 1024);
  bf16x8 vb1 = *(const bf16x8*)(vc + 1536);

  f32x16 S0 = __builtin_amdgcn_mfma_f32_32x32x16_bf16(kf0, qf, zero, 0, 0, 0);

  for (int c = 0; c < 25; ++c) {
    int cn = (c + 2 < 25) ? c + 2 : 24;    // 2-deep prefetch (clamped)
    bf16x8 kf2 = *(const bf16x8*)(kc + (size_t)cn * 512);
    bf16x8 va2 = *(const bf16x8*)(vc + (size_t)cn * 1024);
    bf16x8 vb2 = *(const bf16x8*)(vc + (size_t)cn * 1024 + 512);

    f32x16 S1 = __builtin_amdgcn_mfma_f32_32x32x16_bf16(kf1, qf, zero, 0, 0, 0);

    BF8U f0, f1;
#pragma unroll
    for (int i = 0; i < 4; ++i) {
      f0.u[i] = packbf2(__builtin_amdgcn_exp2f(S0[2 * i]),
                        __builtin_amdgcn_exp2f(S0[2 * i + 1]));
      f1.u[i] = packbf2(__builtin_amdgcn_exp2f(S0[8 + 2 * i]),
                        __builtin_amdgcn_exp2f(S0[9 + 2 * i]));
    }

    acc0 = __builtin_amdgcn_mfma_f32_32x32x16_bf16(va0, f0.v, acc0, 0, 0, 0);
    acc1 = __builtin_amdgcn_mfma_f32_32x32x16_bf16(vb0, f1.v, acc1, 0, 0, 0);

    S0 = S1;
    kf0 = kf1; va0 = va1; vb0 = vb1;
    kf1 = kf2; va1 = va2; vb1 = vb2;
  }

  f32x16 acc;
#pragma unroll
  for (int i = 0; i < 16; ++i) acc[i] = acc0[i] + acc1[i];

  // acc: col q = ln, row d = (r&3)+8*(r>>2)+4*hf. Row16 (denom) = acc[8]@hf0.
  unsigned short* prow =
      &Pb[(size_t)(half * 2 + b) * (NQ * DIM) + (size_t)(q0 + ln) * DIM + h * 16 + 4 * hf];
  uint2 w0, w1;
  w0.x = packbf2(acc[0], acc[1]); w0.y = packbf2(acc[2], acc[3]);
  w1.x = packbf2(acc[4], acc[5]); w1.y = packbf2(acc[6], acc[7]);
  *(uint2*)&prow[0] = w0;
  *(uint2*)&prow[8] = w1;
  if (!hf)
    Lsum[(size_t)(half * 2 + b) * (HEADS * NQ) + (size_t)h * NQ + q0 + ln] = acc[8];
}

// ---------------------------------------------------------------------------
// proj_comb: fused combine (2 halves) + reference scramble + proj GEMM.
// grid (200, 2), block 256.
// ---------------------------------------------------------------------------
__global__ __launch_bounds__(256) void proj_comb(
    const unsigned short* __restrict__ Pb, const float* __restrict__ Lsum,
    const bf16_t* __restrict__ Wb, const float* __restrict__ p_b,
    float* __restrict__ Out)
{
  __shared__ __align__(16) unsigned short As[32][136];
  int t = threadIdx.x;
  int b = blockIdx.y;
  int s0 = blockIdx.x * 32;

  {
    int tx = t & 31, cg = t >> 5;          // lane sweeps s (coalesced in f)
#pragma unroll
    for (int it = 0; it < 16; ++it) {
      int c = cg * 16 + it;
      int f = c * NQ + s0 + tx;            // flat att index = n*128 + h*16+d
      int n = f >> 7, hh = (f >> 4) & 7;
      float p0 = __uint_as_float((unsigned)Pb[(size_t)b * (NQ * DIM) + f] << 16);
      float p1 = __uint_as_float((unsigned)Pb[(size_t)(2 + b) * (NQ * DIM) + f] << 16);
      float L = Lsum[(size_t)b * (HEADS * NQ) + (size_t)hh * NQ + n] +
                Lsum[(size_t)(2 + b) * (HEADS * NQ) + (size_t)hh * NQ + n];
      As[tx][c] = f2bf((p0 + p1) / L);
    }
  }
  __syncthreads();

  int ln = t & 31, hf = (t >> 5) & 1, wid = t >> 6;
  int o = wid * 32 + ln;
  const bf16_t* brow = &Wb[49152 + (size_t)o * DIM + hf * 8];
  const unsigned short* arow = &As[ln][hf * 8];
  f32x16 acc = {};
#pragma unroll
  for (int c0 = 0; c0 < 128; c0 += 16) {
    bf16x8 af = *(const bf16x8*)&arow[c0];
    bf16x8 bf = *(const bf16x8*)&brow[c0];
    acc = __builtin_amdgcn_mfma_f32_32x32x16_bf16(af, bf, acc, 0, 0, 0);
  }
  float bv = p_b[o];
  float* obase = &Out[((size_t)b * DIM + o) * NQ + s0 + 4 * hf];
#pragma unroll
  for (int g = 0; g < 4; ++g) {
    float4 r;
    r.x = acc[4 * g + 0] + bv; r.y = acc[4 * g + 1] + bv;
    r.z = acc[4 * g + 2] + bv; r.w = acc[4 * g + 3] + bv;
    *(float4*)&obase[8 * g] = r;
  }
}

// ---------------------------------------------------------------------------
extern "C" void kernel_launch(void* const* d_in, const int* in_sizes, int n_in,
                              void* d_out, int out_size, void* d_ws, size_t ws_size,
                              hipStream_t stream)
{
  const float* x    = (const float*)d_in[0];
  const float* q_w  = (const float*)d_in[1];
  const float* q_b  = (const float*)d_in[2];
  const float* k_w  = (const float*)d_in[3];
  const float* k_b  = (const float*)d_in[4];
  const float* v_w  = (const float*)d_in[5];
  const float* v_b  = (const float*)d_in[6];
  const float* sr_w = (const float*)d_in[7];
  const float* sr_b = (const float*)d_in[8];
  const float* bng  = (const float*)d_in[9];
  const float* bnb  = (const float*)d_in[10];
  const float* bnm  = (const float*)d_in[11];
  const float* bnv  = (const float*)d_in[12];
  const float* p_w  = (const float*)d_in[13];
  const float* p_b  = (const float*)d_in[14];
  float* out = (float*)d_out;

  float* ws = (float*)d_ws;
  // f32-slot layout, no aliasing (~19.9 MB of the 256+ MB ws):
  bf16_t* Xb   = (bf16_t*)(ws);             // [0, 819200)
  bf16_t* X4b  = (bf16_t*)(ws + 819200);    // [819200, 1638400)
  bf16_t* Qb   = (bf16_t*)(ws + 1638400);   // [1638400, 2457600)
  bf16_t* Kp   = (bf16_t*)(ws + 2457600);   // [2457600, 2662400)
  bf16_t* Vp   = (bf16_t*)(ws + 2662400);   // [2662400, 3072000)
  float*  Lsum = ws + 3072000;              // [3072000, 3276800)
  bf16_t* Wb   = (bf16_t*)(ws + 3276800);   // [3276800, 3342336)
  bf16_t* Pb   = (bf16_t*)(ws + 3342336);   // [3342336, 4980736) 4 slices

  const float sl = 0.25f * LOG2E;  // SCALE * log2(e) folded into Q

  // 1. transpose + coalesced im2col + weight cast + Vp denom fill (fused)
  prep_all<<<dim3(2880), dim3(256), 0, stream>>>(
      x, q_w, k_w, v_w, p_w, sr_w,
      (unsigned short*)Xb, (unsigned short*)Wb,
      (unsigned short*)X4b, (unsigned short*)Vp);

  // 2. sr->k->v (blocks 0-49, LDS-fused) + q (blocks 50-249)
  mgemm_qsrkv<<<dim3(250, NBATCH), dim3(256), 0, stream>>>(
      Xb, X4b, Wb, q_b, sr_b, k_b, v_b, bng, bnb, bnm, bnv,
      (unsigned short*)Qb, (unsigned short*)Kp, (unsigned short*)Vp, sl);

  // 3. attention partials (kv-split = 2, pipelined, natural VGPR allocation)
  attn_split<<<dim3(NQ / 128, HEADS, 4), dim3(256), 0, stream>>>(
      Qb, Kp, Vp, (unsigned short*)Pb, Lsum);

  // 4. combine + scramble + proj -> f32 chan-major final output (B,128,80,80)
  proj_comb<<<dim3(200, NBATCH), dim3(256), 0, stream>>>(
      (const unsigned short*)Pb, Lsum, Wb, p_b, out);
}